// Round 1
// baseline (1203.967 us; speedup 1.0000x reference)
//
#include <hip/hip_runtime.h>

#define HF 128
#define CAP 64

// ---------------- u/v/c fold of nodepost + d_W3 + final ----------------
// feat_out·fw1 = h2 @ (nodepost_W @ fw1)   (since feat_out = h2@Wp + bp)
// dist_out·fw2 = y3 @ (d_W3 @ fw2)
// c = bp·fw1 + b3·fw2 + final_b
__global__ __launch_bounds__(128) void uvc_kernel(
    const float* __restrict__ npW, const float* __restrict__ npb,
    const float* __restrict__ dW3, const float* __restrict__ db3,
    const float* __restrict__ fW,  const float* __restrict__ fb,
    float* __restrict__ uvc)
{
    int i = threadIdx.x;  // 0..127
    float u = 0.f, v = 0.f;
    for (int j = 0; j < HF; ++j) {
        u += npW[i * HF + j] * fW[j];
        v += dW3[i * HF + j] * fW[HF + j];
    }
    uvc[i] = u;
    uvc[HF + i] = v;
    if (i == 0) {
        float c = fb[0];
        for (int j = 0; j < HF; ++j) c += npb[j] * fW[j] + db3[j] * fW[HF + j];
        uvc[2 * HF] = c;
    }
}

// ---------------- bucket build: deg doubles as cursor ----------------
__global__ __launch_bounds__(256) void bucket_kernel(
    const int* __restrict__ eidx, long E,
    int* __restrict__ deg, int* __restrict__ bucket)
{
    long e = (long)blockIdx.x * 256 + threadIdx.x;
    if (e >= E) return;
    int s = eidx[e];        // src row
    int d = eidx[E + e];    // dst row
    int pos = atomicAdd(&deg[d], 1);
    if (pos < CAP) bucket[(long)d * CAP + pos] = s;
}

// ---------------- mean aggregation: one wave per node ----------------
__global__ __launch_bounds__(256) void agg_kernel(
    const float* __restrict__ hin, const int* __restrict__ deg,
    const int* __restrict__ bucket, float* __restrict__ out, int n)
{
    const int wave = threadIdx.x >> 6, lane = threadIdx.x & 63;
    const long node = (long)blockIdx.x * 4 + wave;
    if (node >= n) return;
    const int dg = deg[node];
    const int m  = dg < CAP ? dg : CAP;
    const int* bl = bucket + node * CAP;
    float ax = 0.f, ay = 0.f;
    int e = 0;
    for (; e + 4 <= m; e += 4) {           // 4 independent gathers in flight
        int4 s4 = *(const int4*)(bl + e);
        float2 f0 = *(const float2*)(hin + (long)s4.x * HF + lane * 2);
        float2 f1 = *(const float2*)(hin + (long)s4.y * HF + lane * 2);
        float2 f2 = *(const float2*)(hin + (long)s4.z * HF + lane * 2);
        float2 f3 = *(const float2*)(hin + (long)s4.w * HF + lane * 2);
        ax += f0.x + f1.x + f2.x + f3.x;
        ay += f0.y + f1.y + f2.y + f3.y;
    }
    for (; e < m; ++e) {
        int s = bl[e];
        float2 f = *(const float2*)(hin + (long)s * HF + lane * 2);
        ax += f.x; ay += f.y;
    }
    const float sc = 1.f / (float)(dg > 1 ? dg : 1);
    float2 r; r.x = ax * sc; r.y = ay * sc;
    *(float2*)(out + node * HF + lane * 2) = r;
}

// ---------------- generic fused GEMM: out = act(A1@W1 [+ A2@W2] + b) ----------------
// K = 128 per matrix, 64 rows/block, thread computes 4 rows x 8 cols.
__device__ __forceinline__ void gemm_pass(
    const float* __restrict__ A, int lda, const float* __restrict__ W,
    const long rr[4], int c0, float acc[4][8])
{
    const float* a0 = A + rr[0] * lda;
    const float* a1 = A + rr[1] * lda;
    const float* a2 = A + rr[2] * lda;
    const float* a3 = A + rr[3] * lda;
    #pragma unroll 4
    for (int k = 0; k < HF; k += 4) {
        float4 av[4];
        av[0] = *(const float4*)(a0 + k);
        av[1] = *(const float4*)(a1 + k);
        av[2] = *(const float4*)(a2 + k);
        av[3] = *(const float4*)(a3 + k);
        #pragma unroll
        for (int kk = 0; kk < 4; ++kk) {
            float4 w0 = *(const float4*)(W + (k + kk) * HF + c0);
            float4 w1 = *(const float4*)(W + (k + kk) * HF + c0 + 4);
            #pragma unroll
            for (int r = 0; r < 4; ++r) {
                float a = ((const float*)&av[r])[kk];
                acc[r][0] += a * w0.x; acc[r][1] += a * w0.y;
                acc[r][2] += a * w0.z; acc[r][3] += a * w0.w;
                acc[r][4] += a * w1.x; acc[r][5] += a * w1.y;
                acc[r][6] += a * w1.z; acc[r][7] += a * w1.w;
            }
        }
    }
}

template<bool HAS_A2, bool RELU>
__global__ __launch_bounds__(256) void gemm128_kernel(
    const float* __restrict__ A1, int lda1, const float* __restrict__ W1,
    const float* __restrict__ A2, int lda2, const float* __restrict__ W2,
    const float* __restrict__ bias, float* __restrict__ out, int n)
{
    const int t  = threadIdx.x;
    const int cg = t & 15, rg = t >> 4;
    const int c0 = cg * 8;
    const long rbase = (long)blockIdx.x * 64 + (long)rg * 4;

    float acc[4][8];
    #pragma unroll
    for (int r = 0; r < 4; ++r)
        #pragma unroll
        for (int c = 0; c < 8; ++c) acc[r][c] = 0.f;

    long rr[4];
    #pragma unroll
    for (int r = 0; r < 4; ++r) {
        long q = rbase + r;
        rr[r] = q < n ? q : (long)(n - 1);
    }

    gemm_pass(A1, lda1, W1, rr, c0, acc);
    if (HAS_A2) gemm_pass(A2, lda2, W2, rr, c0, acc);

    float4 b0 = *(const float4*)(bias + c0);
    float4 b1 = *(const float4*)(bias + c0 + 4);
    #pragma unroll
    for (int r = 0; r < 4; ++r) {
        if (rbase + r < n) {
            float o[8];
            o[0] = acc[r][0] + b0.x; o[1] = acc[r][1] + b0.y;
            o[2] = acc[r][2] + b0.z; o[3] = acc[r][3] + b0.w;
            o[4] = acc[r][4] + b1.x; o[5] = acc[r][5] + b1.y;
            o[6] = acc[r][6] + b1.z; o[7] = acc[r][7] + b1.w;
            if (RELU) {
                #pragma unroll
                for (int c = 0; c < 8; ++c) o[c] = fmaxf(o[c], 0.f);
            }
            float4 v0; v0.x = o[0]; v0.y = o[1]; v0.z = o[2]; v0.w = o[3];
            float4 v1; v1.x = o[4]; v1.y = o[5]; v1.z = o[6]; v1.w = o[7];
            *(float4*)(out + (rbase + r) * HF + c0)     = v0;
            *(float4*)(out + (rbase + r) * HF + c0 + 4) = v1;
        }
    }
}

// ---------------- dist MLP layer 0 (K=5) ----------------
__global__ __launch_bounds__(256) void dist0_kernel(
    const float* __restrict__ ea, const float* __restrict__ W0,
    const float* __restrict__ b0, float* __restrict__ out, int n)
{
    long tid = (long)blockIdx.x * 256 + threadIdx.x;
    long row = tid >> 5;
    int  c0  = (int)(tid & 31) * 4;
    if (row >= n) return;
    float4 acc = *(const float4*)(b0 + c0);
    #pragma unroll
    for (int k = 0; k < 5; ++k) {
        float ek = ea[row * 5 + k];
        float4 w = *(const float4*)(W0 + k * HF + c0);
        acc.x += ek * w.x; acc.y += ek * w.y;
        acc.z += ek * w.z; acc.w += ek * w.w;
    }
    acc.x = fmaxf(acc.x, 0.f); acc.y = fmaxf(acc.y, 0.f);
    acc.z = fmaxf(acc.z, 0.f); acc.w = fmaxf(acc.w, 0.f);
    *(float4*)(out + row * HF + c0) = acc;
}

// ---------------- final: sigmoid(h2·u + y3·v + c), one wave per node ----------------
__global__ __launch_bounds__(256) void final_kernel(
    const float* __restrict__ h2, const float* __restrict__ y3,
    const float* __restrict__ uvc, float* __restrict__ out, int n)
{
    const int wave = threadIdx.x >> 6, lane = threadIdx.x & 63;
    const long node = (long)blockIdx.x * 4 + wave;
    if (node >= n) return;
    float2 u = *(const float2*)(uvc + lane * 2);
    float2 v = *(const float2*)(uvc + HF + lane * 2);
    float2 a = *(const float2*)(h2 + node * HF + lane * 2);
    float2 b = *(const float2*)(y3 + node * HF + lane * 2);
    float s = a.x * u.x + a.y * u.y + b.x * v.x + b.y * v.y;
    #pragma unroll
    for (int off = 32; off > 0; off >>= 1) s += __shfl_xor(s, off, 64);
    if (lane == 0) {
        float c = uvc[2 * HF];
        out[node] = 1.f / (1.f + expf(-(s + c)));
    }
}

extern "C" void kernel_launch(void* const* d_in, const int* in_sizes, int n_in,
                              void* d_out, int out_size, void* d_ws, size_t ws_size,
                              hipStream_t stream)
{
    const float* x      = (const float*)d_in[0];
    const int*   eidx   = (const int*)  d_in[1];
    const float* eattr  = (const float*)d_in[2];
    const float* pre_W  = (const float*)d_in[3];
    const float* pre_b  = (const float*)d_in[4];
    const float* c1_Ws  = (const float*)d_in[5];
    const float* c1_Wn  = (const float*)d_in[6];
    const float* c1_b   = (const float*)d_in[7];
    const float* c2_Ws  = (const float*)d_in[8];
    const float* c2_Wn  = (const float*)d_in[9];
    const float* c2_b   = (const float*)d_in[10];
    const float* npW    = (const float*)d_in[11];
    const float* npb    = (const float*)d_in[12];
    const float* dW0    = (const float*)d_in[13];
    const float* db0    = (const float*)d_in[14];
    const float* dW1    = (const float*)d_in[15];
    const float* db1    = (const float*)d_in[16];
    const float* dW2    = (const float*)d_in[17];
    const float* db2    = (const float*)d_in[18];
    const float* dW3    = (const float*)d_in[19];
    const float* db3    = (const float*)d_in[20];
    const float* fW     = (const float*)d_in[21];
    const float* fb     = (const float*)d_in[22];

    const int  n = in_sizes[0] / 256;   // N (F_IN = 256)
    const long E = in_sizes[1] / 2;

    char* ws = (char*)d_ws;
    size_t off = 0;
    auto alloc = [&](size_t bytes) -> void* {
        void* p = ws + off;
        off += (bytes + 255) & ~(size_t)255;
        return p;
    };
    float* B0     = (float*)alloc((size_t)n * HF * sizeof(float)); // h0 -> h2
    float* B1     = (float*)alloc((size_t)n * HF * sizeof(float)); // agg -> yL0 -> yL2
    float* B2     = (float*)alloc((size_t)n * HF * sizeof(float)); // h1 -> yL1
    int*   deg    = (int*)  alloc((size_t)n * sizeof(int));
    int*   bucket = (int*)  alloc((size_t)n * CAP * sizeof(int));
    float* uvc    = (float*)alloc((2 * HF + 1) * sizeof(float));

    const int gemmBlocks = (n + 63) / 64;
    const int nodeBlocks = (n + 3) / 4;

    // independent small precompute
    uvc_kernel<<<1, 128, 0, stream>>>(npW, npb, dW3, db3, fW, fb, uvc);

    // degree + bucket (deg is the cursor)
    hipMemsetAsync(deg, 0, (size_t)n * sizeof(int), stream);
    bucket_kernel<<<(int)((E + 255) / 256), 256, 0, stream>>>(eidx, E, deg, bucket);

    // h0 = x @ pre_W + pre_b   (split K=256 into two K=128 passes)
    gemm128_kernel<true, false><<<gemmBlocks, 256, 0, stream>>>(
        x, 256, pre_W, x + HF, 256, pre_W + HF * HF, pre_b, B0, n);

    // agg1 = mean_agg(h0)
    agg_kernel<<<nodeBlocks, 256, 0, stream>>>(B0, deg, bucket, B1, n);

    // h1 = relu(h0@c1_Ws + agg1@c1_Wn + c1_b)
    gemm128_kernel<true, true><<<gemmBlocks, 256, 0, stream>>>(
        B0, HF, c1_Ws, B1, HF, c1_Wn, c1_b, B2, n);

    // agg2 = mean_agg(h1)
    agg_kernel<<<nodeBlocks, 256, 0, stream>>>(B2, deg, bucket, B1, n);

    // h2 = relu(h1@c2_Ws + agg2@c2_Wn + c2_b)  -> B0
    gemm128_kernel<true, true><<<gemmBlocks, 256, 0, stream>>>(
        B2, HF, c2_Ws, B1, HF, c2_Wn, c2_b, B0, n);

    // dist path
    dist0_kernel<<<(int)(((long)n * 32 + 255) / 256), 256, 0, stream>>>(
        eattr, dW0, db0, B1, n);
    gemm128_kernel<false, true><<<gemmBlocks, 256, 0, stream>>>(
        B1, HF, dW1, nullptr, 0, nullptr, db1, B2, n);
    gemm128_kernel<false, true><<<gemmBlocks, 256, 0, stream>>>(
        B2, HF, dW2, nullptr, 0, nullptr, db2, B1, n);

    // out = sigmoid(h2·u + y3·v + c)
    final_kernel<<<nodeBlocks, 256, 0, stream>>>(B0, B1, uvc, (float*)d_out, n);
}

// Round 2
// 458.955 us; speedup vs baseline: 2.6233x; 2.6233x over previous
//
#include <hip/hip_runtime.h>

#define HF 128
#define CAP 64

typedef __attribute__((ext_vector_type(8))) short s16x8;
typedef __attribute__((ext_vector_type(4))) float f32x4;

__device__ __forceinline__ unsigned short f2bf(float f) {
    unsigned u = __float_as_uint(f);
    return (unsigned short)((u + 0x7fff + ((u >> 16) & 1)) >> 16);
}
__device__ __forceinline__ float bflo(unsigned u) { return __uint_as_float(u << 16); }
__device__ __forceinline__ float bfhi(unsigned u) { return __uint_as_float(u & 0xffff0000u); }

// ---------------- weight repack: fp32 [K][128] -> bf16 B-fragment order ----------------
// Wp[((nt*(K/32)+kt)*64+lane)*8+j] = bf16(W[kt*32+(lane>>4)*8+j][nt*16+(lane&15)])
__global__ __launch_bounds__(256) void repack_kernel(
    const float* __restrict__ W, short* __restrict__ Wp, int K)
{
    int t = blockIdx.x * 256 + threadIdx.x;
    int nkt = K >> 5;
    if (t >= 8 * nkt * 64) return;
    int lane = t & 63;
    int kt = (t >> 6) % nkt;
    int nt = (t >> 6) / nkt;
    int c = nt * 16 + (lane & 15);
    int kbase = kt * 32 + (lane >> 4) * 8;
    s16x8 v;
    #pragma unroll
    for (int j = 0; j < 8; ++j) v[j] = (short)f2bf(W[(long)(kbase + j) * HF + c]);
    *(s16x8*)(Wp + (long)t * 8) = v;
}

// ---------------- u/v/c fold of nodepost + d_W3 + final ----------------
__global__ __launch_bounds__(128) void uvc_kernel(
    const float* __restrict__ npW, const float* __restrict__ npb,
    const float* __restrict__ dW3, const float* __restrict__ db3,
    const float* __restrict__ fW,  const float* __restrict__ fb,
    float* __restrict__ uvc)
{
    int i = threadIdx.x;
    float u = 0.f, v = 0.f;
    for (int j = 0; j < HF; ++j) {
        u += npW[i * HF + j] * fW[j];
        v += dW3[i * HF + j] * fW[HF + j];
    }
    uvc[i] = u;
    uvc[HF + i] = v;
    if (i == 0) {
        float c = fb[0];
        for (int j = 0; j < HF; ++j) c += npb[j] * fW[j] + db3[j] * fW[HF + j];
        uvc[2 * HF] = c;
    }
}

// ---------------- bucket build ----------------
__global__ __launch_bounds__(256) void bucket_kernel(
    const int* __restrict__ eidx, long E,
    int* __restrict__ deg, int* __restrict__ bucket)
{
    long e = (long)blockIdx.x * 256 + threadIdx.x;
    if (e >= E) return;
    int s = eidx[e];
    int d = eidx[E + e];
    int pos = atomicAdd(&deg[d], 1);
    if (pos < CAP) bucket[(long)d * CAP + pos] = s;
}

// ---------------- mean aggregation (bf16 in/out, fp32 accum) ----------------
__global__ __launch_bounds__(256) void agg_kernel(
    const unsigned short* __restrict__ hin, const int* __restrict__ deg,
    const int* __restrict__ bucket, unsigned short* __restrict__ out, int n)
{
    const int wave = threadIdx.x >> 6, lane = threadIdx.x & 63;
    const long node = (long)blockIdx.x * 4 + wave;
    if (node >= n) return;
    const int dg = deg[node];
    const int m  = dg < CAP ? dg : CAP;
    const int* bl = bucket + node * CAP;
    float ax = 0.f, ay = 0.f;
    int e = 0;
    for (; e + 4 <= m; e += 4) {
        int4 s4 = *(const int4*)(bl + e);
        unsigned u0 = *(const unsigned*)(hin + (long)s4.x * HF + lane * 2);
        unsigned u1 = *(const unsigned*)(hin + (long)s4.y * HF + lane * 2);
        unsigned u2 = *(const unsigned*)(hin + (long)s4.z * HF + lane * 2);
        unsigned u3 = *(const unsigned*)(hin + (long)s4.w * HF + lane * 2);
        ax += bflo(u0) + bflo(u1) + bflo(u2) + bflo(u3);
        ay += bfhi(u0) + bfhi(u1) + bfhi(u2) + bfhi(u3);
    }
    for (; e < m; ++e) {
        unsigned u = *(const unsigned*)(hin + (long)bl[e] * HF + lane * 2);
        ax += bflo(u); ay += bfhi(u);
    }
    const float sc = 1.f / (float)(dg > 1 ? dg : 1);
    unsigned r = (unsigned)f2bf(ax * sc) | ((unsigned)f2bf(ay * sc) << 16);
    *(unsigned*)(out + node * HF + lane * 2) = r;
}

// ---------------- MFMA GEMM pass over one A/W pair ----------------
template<int K, bool F32>
__device__ __forceinline__ void gemm_pass_mfma(
    const void* __restrict__ Av, const short* __restrict__ Wp,
    long rA, int lane, f32x4 acc[8])
{
    const int q = lane >> 4;
    constexpr int NKT = K >> 5;
    #pragma unroll
    for (int kt = 0; kt < NKT; ++kt) {
        s16x8 a;
        if (F32) {
            const float* p = (const float*)Av + rA * K + kt * 32 + q * 8;
            float4 f0 = *(const float4*)p;
            float4 f1 = *(const float4*)(p + 4);
            a[0] = (short)f2bf(f0.x); a[1] = (short)f2bf(f0.y);
            a[2] = (short)f2bf(f0.z); a[3] = (short)f2bf(f0.w);
            a[4] = (short)f2bf(f1.x); a[5] = (short)f2bf(f1.y);
            a[6] = (short)f2bf(f1.z); a[7] = (short)f2bf(f1.w);
        } else {
            a = *(const s16x8*)((const unsigned short*)Av + rA * K + kt * 32 + q * 8);
        }
        #pragma unroll
        for (int nt = 0; nt < 8; ++nt) {
            s16x8 b = *(const s16x8*)(Wp + ((long)(nt * NKT + kt) * 64 + lane) * 8);
            acc[nt] = __builtin_amdgcn_mfma_f32_16x16x32_bf16(a, b, acc[nt], 0, 0, 0);
        }
    }
}

// out = act(A1@W1 [+ A2@W2] + b); 4 waves/block, 16 rows/wave
template<int K1, bool A1F32, bool HAS_A2, bool RELU>
__global__ __launch_bounds__(256) void mfma_gemm(
    const void* __restrict__ A1, const short* __restrict__ W1p,
    const unsigned short* __restrict__ A2, const short* __restrict__ W2p,
    const float* __restrict__ bias, unsigned short* __restrict__ out, int n)
{
    const int lane = threadIdx.x & 63;
    const int wv   = threadIdx.x >> 6;
    const long row0 = (long)blockIdx.x * 64 + wv * 16;

    f32x4 acc[8];
    #pragma unroll
    for (int nt = 0; nt < 8; ++nt)
        #pragma unroll
        for (int i = 0; i < 4; ++i) acc[nt][i] = 0.f;

    long rA = row0 + (lane & 15);
    if (rA > n - 1) rA = n - 1;

    gemm_pass_mfma<K1, A1F32>(A1, W1p, rA, lane, acc);
    if (HAS_A2) gemm_pass_mfma<HF, false>((const void*)A2, W2p, rA, lane, acc);

    const int cq = lane >> 4;
    #pragma unroll
    for (int nt = 0; nt < 8; ++nt) {
        int col = nt * 16 + (lane & 15);
        float bs = bias[col];
        #pragma unroll
        for (int i = 0; i < 4; ++i) {
            long r = row0 + cq * 4 + i;
            if (r < n) {
                float o = acc[nt][i] + bs;
                if (RELU) o = fmaxf(o, 0.f);
                out[r * HF + col] = f2bf(o);
            }
        }
    }
}

// ---------------- dist MLP layer 0 (K=5), bf16 out ----------------
__global__ __launch_bounds__(256) void dist0_kernel(
    const float* __restrict__ ea, const float* __restrict__ W0,
    const float* __restrict__ b0, unsigned short* __restrict__ out, int n)
{
    long tid = (long)blockIdx.x * 256 + threadIdx.x;
    long row = tid >> 5;
    int  c0  = (int)(tid & 31) * 4;
    if (row >= n) return;
    float4 acc = *(const float4*)(b0 + c0);
    #pragma unroll
    for (int k = 0; k < 5; ++k) {
        float ek = ea[row * 5 + k];
        float4 w = *(const float4*)(W0 + k * HF + c0);
        acc.x += ek * w.x; acc.y += ek * w.y;
        acc.z += ek * w.z; acc.w += ek * w.w;
    }
    unsigned long long pk =
        (unsigned long long)f2bf(fmaxf(acc.x, 0.f)) |
        ((unsigned long long)f2bf(fmaxf(acc.y, 0.f)) << 16) |
        ((unsigned long long)f2bf(fmaxf(acc.z, 0.f)) << 32) |
        ((unsigned long long)f2bf(fmaxf(acc.w, 0.f)) << 48);
    *(unsigned long long*)(out + row * HF + c0) = pk;
}

// ---------------- final: sigmoid(h2·u + y2·v + c) ----------------
__global__ __launch_bounds__(256) void final_kernel(
    const unsigned short* __restrict__ h2, const unsigned short* __restrict__ y2,
    const float* __restrict__ uvc, float* __restrict__ out, int n)
{
    const int wave = threadIdx.x >> 6, lane = threadIdx.x & 63;
    const long node = (long)blockIdx.x * 4 + wave;
    if (node >= n) return;
    float2 u = *(const float2*)(uvc + lane * 2);
    float2 v = *(const float2*)(uvc + HF + lane * 2);
    unsigned a = *(const unsigned*)(h2 + node * HF + lane * 2);
    unsigned b = *(const unsigned*)(y2 + node * HF + lane * 2);
    float s = bflo(a) * u.x + bfhi(a) * u.y + bflo(b) * v.x + bfhi(b) * v.y;
    #pragma unroll
    for (int off = 32; off > 0; off >>= 1) s += __shfl_xor(s, off, 64);
    if (lane == 0) {
        float c = uvc[2 * HF];
        out[node] = 1.f / (1.f + expf(-(s + c)));
    }
}

extern "C" void kernel_launch(void* const* d_in, const int* in_sizes, int n_in,
                              void* d_out, int out_size, void* d_ws, size_t ws_size,
                              hipStream_t stream)
{
    const float* x      = (const float*)d_in[0];
    const int*   eidx   = (const int*)  d_in[1];
    const float* eattr  = (const float*)d_in[2];
    const float* pre_W  = (const float*)d_in[3];
    const float* pre_b  = (const float*)d_in[4];
    const float* c1_Ws  = (const float*)d_in[5];
    const float* c1_Wn  = (const float*)d_in[6];
    const float* c1_b   = (const float*)d_in[7];
    const float* c2_Ws  = (const float*)d_in[8];
    const float* c2_Wn  = (const float*)d_in[9];
    const float* c2_b   = (const float*)d_in[10];
    const float* npW    = (const float*)d_in[11];
    const float* npb    = (const float*)d_in[12];
    const float* dW0    = (const float*)d_in[13];
    const float* db0    = (const float*)d_in[14];
    const float* dW1    = (const float*)d_in[15];
    const float* db1    = (const float*)d_in[16];
    const float* dW2    = (const float*)d_in[17];
    const float* db2    = (const float*)d_in[18];
    const float* dW3    = (const float*)d_in[19];
    const float* db3    = (const float*)d_in[20];
    const float* fW     = (const float*)d_in[21];
    const float* fb     = (const float*)d_in[22];

    const int  n = in_sizes[0] / 256;
    const long E = in_sizes[1] / 2;

    char* ws = (char*)d_ws;
    size_t off = 0;
    auto alloc = [&](size_t bytes) -> void* {
        void* p = ws + off;
        off += (bytes + 255) & ~(size_t)255;
        return p;
    };
    unsigned short* B0 = (unsigned short*)alloc((size_t)n * HF * 2);
    unsigned short* B1 = (unsigned short*)alloc((size_t)n * HF * 2);
    unsigned short* B2 = (unsigned short*)alloc((size_t)n * HF * 2);
    int*   deg    = (int*)alloc((size_t)n * sizeof(int));
    int*   bucket = (int*)alloc((size_t)n * CAP * sizeof(int));
    float* uvc    = (float*)alloc((2 * HF + 1) * sizeof(float));
    short* preWp  = (short*)alloc(256 * HF * 2);
    short* c1Wsp  = (short*)alloc(HF * HF * 2);
    short* c1Wnp  = (short*)alloc(HF * HF * 2);
    short* c2Wsp  = (short*)alloc(HF * HF * 2);
    short* c2Wnp  = (short*)alloc(HF * HF * 2);
    short* dW1p   = (short*)alloc(HF * HF * 2);
    short* dW2p   = (short*)alloc(HF * HF * 2);

    const int gemmBlocks = (n + 63) / 64;
    const int nodeBlocks = (n + 3) / 4;

    // weight repacks + small precompute (all independent)
    repack_kernel<<<16, 256, 0, stream>>>(pre_W, preWp, 256);
    repack_kernel<<<8, 256, 0, stream>>>(c1_Ws, c1Wsp, HF);
    repack_kernel<<<8, 256, 0, stream>>>(c1_Wn, c1Wnp, HF);
    repack_kernel<<<8, 256, 0, stream>>>(c2_Ws, c2Wsp, HF);
    repack_kernel<<<8, 256, 0, stream>>>(c2_Wn, c2Wnp, HF);
    repack_kernel<<<8, 256, 0, stream>>>(dW1, dW1p, HF);
    repack_kernel<<<8, 256, 0, stream>>>(dW2, dW2p, HF);
    uvc_kernel<<<1, 128, 0, stream>>>(npW, npb, dW3, db3, fW, fb, uvc);

    hipMemsetAsync(deg, 0, (size_t)n * sizeof(int), stream);
    bucket_kernel<<<(int)((E + 255) / 256), 256, 0, stream>>>(eidx, E, deg, bucket);

    // h0 = x @ pre_W + pre_b (K=256, fp32 A converted inline)
    mfma_gemm<256, true, false, false><<<gemmBlocks, 256, 0, stream>>>(
        x, preWp, nullptr, nullptr, pre_b, B0, n);

    // agg1 = mean_agg(h0)
    agg_kernel<<<nodeBlocks, 256, 0, stream>>>(B0, deg, bucket, B1, n);

    // h1 = relu(h0@c1_Ws + agg1@c1_Wn + c1_b)
    mfma_gemm<HF, false, true, true><<<gemmBlocks, 256, 0, stream>>>(
        B0, c1Wsp, B1, c1Wnp, c1_b, B2, n);

    // agg2 = mean_agg(h1)
    agg_kernel<<<nodeBlocks, 256, 0, stream>>>(B2, deg, bucket, B1, n);

    // h2 = relu(h1@c2_Ws + agg2@c2_Wn + c2_b)
    mfma_gemm<HF, false, true, true><<<gemmBlocks, 256, 0, stream>>>(
        B2, c2Wsp, B1, c2Wnp, c2_b, B0, n);

    // dist path
    dist0_kernel<<<(int)(((long)n * 32 + 255) / 256), 256, 0, stream>>>(
        eattr, dW0, db0, B1, n);
    mfma_gemm<HF, false, false, true><<<gemmBlocks, 256, 0, stream>>>(
        B1, dW1p, nullptr, nullptr, db1, B2, n);
    mfma_gemm<HF, false, false, true><<<gemmBlocks, 256, 0, stream>>>(
        B2, dW2p, nullptr, nullptr, db2, B1, n);

    // out = sigmoid(h2·u + y2·v + c)
    final_kernel<<<nodeBlocks, 256, 0, stream>>>(B0, B1, uvc, (float*)d_out, n);
}

// Round 3
// 387.273 us; speedup vs baseline: 3.1088x; 1.1851x over previous
//
#include <hip/hip_runtime.h>

#define HF 128
#define CAP 64
#define PSHIFT 13   // bucket sub-pass granularity: 8192 nodes -> 2MB region / pass

typedef __attribute__((ext_vector_type(8))) short s16x8;
typedef __attribute__((ext_vector_type(4))) float f32x4;

__device__ __forceinline__ unsigned short f2bf(float f) {
    unsigned u = __float_as_uint(f);
    return (unsigned short)((u + 0x7fff + ((u >> 16) & 1)) >> 16);
}
__device__ __forceinline__ float bflo(unsigned u) { return __uint_as_float(u << 16); }
__device__ __forceinline__ float bfhi(unsigned u) { return __uint_as_float(u & 0xffff0000u); }

// ---------------- one-launch repack of all weights + uvc fold ----------------
// Wp[((nt*(K/32)+kt)*64+lane)*8+j] = bf16(W[kt*32+(lane>>4)*8+j][nt*16+(lane&15)])
__device__ __forceinline__ void repack_one(
    const float* __restrict__ W, short* __restrict__ Wp, int K, int t)
{
    int nkt = K >> 5;
    int lane = t & 63;
    int kt = (t >> 6) % nkt;
    int nt = (t >> 6) / nkt;
    int c = nt * 16 + (lane & 15);
    int kbase = kt * 32 + (lane >> 4) * 8;
    s16x8 v;
    #pragma unroll
    for (int j = 0; j < 8; ++j) v[j] = (short)f2bf(W[(long)(kbase + j) * HF + c]);
    *(s16x8*)(Wp + (long)t * 8) = v;
}

__global__ __launch_bounds__(256) void repack_all(
    const float* __restrict__ preW, const float* __restrict__ c1Ws,
    const float* __restrict__ c1Wn, const float* __restrict__ c2Ws,
    const float* __restrict__ c2Wn, const float* __restrict__ dW1,
    const float* __restrict__ dW2,
    short* preWp, short* c1Wsp, short* c1Wnp, short* c2Wsp, short* c2Wnp,
    short* dW1p, short* dW2p,
    const float* __restrict__ npW, const float* __restrict__ npb,
    const float* __restrict__ dW3, const float* __restrict__ db3,
    const float* __restrict__ fW,  const float* __restrict__ fb,
    float* __restrict__ uvc)
{
    int b = blockIdx.x;
    if (b == 64) {  // uvc fold
        int i = threadIdx.x;
        if (i < HF) {
            float u = 0.f, v = 0.f;
            for (int j = 0; j < HF; ++j) {
                u += npW[i * HF + j] * fW[j];
                v += dW3[i * HF + j] * fW[HF + j];
            }
            uvc[i] = u;
            uvc[HF + i] = v;
            if (i == 0) {
                float c = fb[0];
                for (int j = 0; j < HF; ++j) c += npb[j] * fW[j] + db3[j] * fW[HF + j];
                uvc[2 * HF] = c;
            }
        }
        return;
    }
    if (b < 16) { repack_one(preW, preWp, 256, b * 256 + threadIdx.x); return; }
    int m = (b - 16) >> 3, t = ((b - 16) & 7) * 256 + threadIdx.x;
    const float* W; short* Wp;
    switch (m) {
        case 0: W = c1Ws; Wp = c1Wsp; break;
        case 1: W = c1Wn; Wp = c1Wnp; break;
        case 2: W = c2Ws; Wp = c2Wsp; break;
        case 3: W = c2Wn; Wp = c2Wnp; break;
        case 4: W = dW1;  Wp = dW1p;  break;
        default: W = dW2; Wp = dW2p;  break;
    }
    repack_one(W, Wp, HF, t);
}

// ---------------- bucket build: temporally binned by dst range ----------------
__global__ __launch_bounds__(256) void bucket_kernel(
    const int* __restrict__ eidx, long E,
    int* __restrict__ deg, int* __restrict__ bucket, int npass)
{
    const long per = (E + gridDim.x - 1) / gridDim.x;
    const long e0 = (long)blockIdx.x * per;
    const long e1 = (e0 + per < E) ? e0 + per : E;
    for (int p = 0; p < npass; ++p) {
        for (long e = e0 + threadIdx.x; e < e1; e += 256) {
            int d = eidx[E + e];
            if ((d >> PSHIFT) != p) continue;
            int s = eidx[e];
            int pos = atomicAdd(&deg[d], 1);
            if (pos < CAP) bucket[(long)d * CAP + pos] = s;
        }
    }
}

// ---------------- mean aggregation (bf16 in/out, fp32 accum) ----------------
__global__ __launch_bounds__(256) void agg_kernel(
    const unsigned short* __restrict__ hin, const int* __restrict__ deg,
    const int* __restrict__ bucket, unsigned short* __restrict__ out, int n)
{
    const int wave = threadIdx.x >> 6, lane = threadIdx.x & 63;
    const long node = (long)blockIdx.x * 4 + wave;
    if (node >= n) return;
    const int dg = deg[node];
    const int m  = dg < CAP ? dg : CAP;
    const int* bl = bucket + node * CAP;
    float ax = 0.f, ay = 0.f;
    int e = 0;
    for (; e + 4 <= m; e += 4) {
        int4 s4 = *(const int4*)(bl + e);
        unsigned u0 = *(const unsigned*)(hin + (long)s4.x * HF + lane * 2);
        unsigned u1 = *(const unsigned*)(hin + (long)s4.y * HF + lane * 2);
        unsigned u2 = *(const unsigned*)(hin + (long)s4.z * HF + lane * 2);
        unsigned u3 = *(const unsigned*)(hin + (long)s4.w * HF + lane * 2);
        ax += bflo(u0) + bflo(u1) + bflo(u2) + bflo(u3);
        ay += bfhi(u0) + bfhi(u1) + bfhi(u2) + bfhi(u3);
    }
    for (; e < m; ++e) {
        unsigned u = *(const unsigned*)(hin + (long)bl[e] * HF + lane * 2);
        ax += bflo(u); ay += bfhi(u);
    }
    const float sc = 1.f / (float)(dg > 1 ? dg : 1);
    unsigned r = (unsigned)f2bf(ax * sc) | ((unsigned)f2bf(ay * sc) << 16);
    *(unsigned*)(out + node * HF + lane * 2) = r;
}

// ---------------- MFMA GEMM pass over one A/W pair ----------------
template<int K, bool F32>
__device__ __forceinline__ void gemm_pass_mfma(
    const void* __restrict__ Av, const short* __restrict__ Wp,
    long rA, int lane, f32x4 acc[8])
{
    const int q = lane >> 4;
    constexpr int NKT = K >> 5;
    #pragma unroll
    for (int kt = 0; kt < NKT; ++kt) {
        s16x8 a;
        if (F32) {
            const float* p = (const float*)Av + rA * K + kt * 32 + q * 8;
            float4 f0 = *(const float4*)p;
            float4 f1 = *(const float4*)(p + 4);
            a[0] = (short)f2bf(f0.x); a[1] = (short)f2bf(f0.y);
            a[2] = (short)f2bf(f0.z); a[3] = (short)f2bf(f0.w);
            a[4] = (short)f2bf(f1.x); a[5] = (short)f2bf(f1.y);
            a[6] = (short)f2bf(f1.z); a[7] = (short)f2bf(f1.w);
        } else {
            a = *(const s16x8*)((const unsigned short*)Av + rA * K + kt * 32 + q * 8);
        }
        #pragma unroll
        for (int nt = 0; nt < 8; ++nt) {
            s16x8 b = *(const s16x8*)(Wp + ((long)(nt * NKT + kt) * 64 + lane) * 8);
            acc[nt] = __builtin_amdgcn_mfma_f32_16x16x32_bf16(a, b, acc[nt], 0, 0, 0);
        }
    }
}

// out = act(A1@W1 [+ A2@W2] + b); 4 waves/block, 16 rows/wave
template<int K1, bool A1F32, bool HAS_A2, bool RELU>
__global__ __launch_bounds__(256) void mfma_gemm(
    const void* __restrict__ A1, const short* __restrict__ W1p,
    const unsigned short* __restrict__ A2, const short* __restrict__ W2p,
    const float* __restrict__ bias, unsigned short* __restrict__ out, int n)
{
    const int lane = threadIdx.x & 63;
    const int wv   = threadIdx.x >> 6;
    const long row0 = (long)blockIdx.x * 64 + wv * 16;

    f32x4 acc[8];
    #pragma unroll
    for (int nt = 0; nt < 8; ++nt)
        #pragma unroll
        for (int i = 0; i < 4; ++i) acc[nt][i] = 0.f;

    long rA = row0 + (lane & 15);
    if (rA > n - 1) rA = n - 1;

    gemm_pass_mfma<K1, A1F32>(A1, W1p, rA, lane, acc);
    if (HAS_A2) gemm_pass_mfma<HF, false>((const void*)A2, W2p, rA, lane, acc);

    const int cq = lane >> 4;
    #pragma unroll
    for (int nt = 0; nt < 8; ++nt) {
        int col = nt * 16 + (lane & 15);
        float bs = bias[col];
        #pragma unroll
        for (int i = 0; i < 4; ++i) {
            long r = row0 + cq * 4 + i;
            if (r < n) {
                float o = acc[nt][i] + bs;
                if (RELU) o = fmaxf(o, 0.f);
                out[r * HF + col] = f2bf(o);
            }
        }
    }
}

// ---------------- fused dist head: y1 = relu(relu(ea@W0+b0)@W1+b1) ----------------
__global__ __launch_bounds__(256) void disthead_kernel(
    const float* __restrict__ ea, const float* __restrict__ W0,
    const float* __restrict__ b0, const short* __restrict__ W1p,
    const float* __restrict__ b1, unsigned short* __restrict__ out, int n)
{
    const int lane = threadIdx.x & 63;
    const int wv   = threadIdx.x >> 6;
    const long row0 = (long)blockIdx.x * 64 + wv * 16;
    const int q = lane >> 4;

    long rA = row0 + (lane & 15);
    if (rA > n - 1) rA = n - 1;

    float e0 = ea[rA * 5 + 0], e1 = ea[rA * 5 + 1], e2 = ea[rA * 5 + 2],
          e3 = ea[rA * 5 + 3], e4 = ea[rA * 5 + 4];

    f32x4 acc[8];
    #pragma unroll
    for (int nt = 0; nt < 8; ++nt)
        #pragma unroll
        for (int i = 0; i < 4; ++i) acc[nt][i] = 0.f;

    #pragma unroll
    for (int kt = 0; kt < 4; ++kt) {
        const int c = kt * 32 + q * 8;
        s16x8 a;
        #pragma unroll
        for (int h = 0; h < 2; ++h) {
            float4 w0 = *(const float4*)(W0 + 0 * HF + c + h * 4);
            float4 w1 = *(const float4*)(W0 + 1 * HF + c + h * 4);
            float4 w2 = *(const float4*)(W0 + 2 * HF + c + h * 4);
            float4 w3 = *(const float4*)(W0 + 3 * HF + c + h * 4);
            float4 w4 = *(const float4*)(W0 + 4 * HF + c + h * 4);
            float4 bb = *(const float4*)(b0 + c + h * 4);
            float y0 = fmaxf(bb.x + e0 * w0.x + e1 * w1.x + e2 * w2.x + e3 * w3.x + e4 * w4.x, 0.f);
            float y1 = fmaxf(bb.y + e0 * w0.y + e1 * w1.y + e2 * w2.y + e3 * w3.y + e4 * w4.y, 0.f);
            float y2 = fmaxf(bb.z + e0 * w0.z + e1 * w1.z + e2 * w2.z + e3 * w3.z + e4 * w4.z, 0.f);
            float y3 = fmaxf(bb.w + e0 * w0.w + e1 * w1.w + e2 * w2.w + e3 * w3.w + e4 * w4.w, 0.f);
            a[h * 4 + 0] = (short)f2bf(y0); a[h * 4 + 1] = (short)f2bf(y1);
            a[h * 4 + 2] = (short)f2bf(y2); a[h * 4 + 3] = (short)f2bf(y3);
        }
        #pragma unroll
        for (int nt = 0; nt < 8; ++nt) {
            s16x8 b = *(const s16x8*)(W1p + ((long)(nt * 4 + kt) * 64 + lane) * 8);
            acc[nt] = __builtin_amdgcn_mfma_f32_16x16x32_bf16(a, b, acc[nt], 0, 0, 0);
        }
    }

    const int cq = lane >> 4;
    #pragma unroll
    for (int nt = 0; nt < 8; ++nt) {
        int col = nt * 16 + (lane & 15);
        float bs = b1[col];
        #pragma unroll
        for (int i = 0; i < 4; ++i) {
            long r = row0 + cq * 4 + i;
            if (r < n) out[r * HF + col] = f2bf(fmaxf(acc[nt][i] + bs, 0.f));
        }
    }
}

// ---------------- fused tail: h2 = relu(h1@c2Ws + agg2@c2Wn + b); y2 = relu(y1@W2+b2);
//                  out = sigmoid(h2·u + y2·v + c) ----------------
__global__ __launch_bounds__(256) void tail_kernel(
    const unsigned short* __restrict__ h1, const unsigned short* __restrict__ agg2,
    const unsigned short* __restrict__ y1,
    const short* __restrict__ c2Wsp, const short* __restrict__ c2Wnp,
    const short* __restrict__ dW2p,
    const float* __restrict__ c2b, const float* __restrict__ db2,
    const float* __restrict__ uvc, float* __restrict__ out, int n)
{
    const int lane = threadIdx.x & 63;
    const int wv   = threadIdx.x >> 6;
    const long row0 = (long)blockIdx.x * 64 + wv * 16;

    f32x4 acch[8], accy[8];
    #pragma unroll
    for (int nt = 0; nt < 8; ++nt)
        #pragma unroll
        for (int i = 0; i < 4; ++i) { acch[nt][i] = 0.f; accy[nt][i] = 0.f; }

    long rA = row0 + (lane & 15);
    if (rA > n - 1) rA = n - 1;

    gemm_pass_mfma<HF, false>((const void*)h1,   c2Wsp, rA, lane, acch);
    gemm_pass_mfma<HF, false>((const void*)agg2, c2Wnp, rA, lane, acch);
    gemm_pass_mfma<HF, false>((const void*)y1,   dW2p,  rA, lane, accy);

    const int cq = lane >> 4;
    float part[4] = {0.f, 0.f, 0.f, 0.f};
    #pragma unroll
    for (int nt = 0; nt < 8; ++nt) {
        int col = nt * 16 + (lane & 15);
        float bh = c2b[col], by = db2[col];
        float uu = uvc[col], vv = uvc[HF + col];
        #pragma unroll
        for (int i = 0; i < 4; ++i) {
            float oh = fmaxf(acch[nt][i] + bh, 0.f);
            float oy = fmaxf(accy[nt][i] + by, 0.f);
            part[i] += oh * uu + oy * vv;
        }
    }
    // reduce over the 16 lanes sharing cq
    #pragma unroll
    for (int i = 0; i < 4; ++i) {
        float s = part[i];
        s += __shfl_xor(s, 1, 64);
        s += __shfl_xor(s, 2, 64);
        s += __shfl_xor(s, 4, 64);
        s += __shfl_xor(s, 8, 64);
        part[i] = s;
    }
    if ((lane & 15) == 0) {
        float c = uvc[2 * HF];
        #pragma unroll
        for (int i = 0; i < 4; ++i) {
            long r = row0 + cq * 4 + i;
            if (r < n) out[r] = 1.f / (1.f + expf(-(part[i] + c)));
        }
    }
}

extern "C" void kernel_launch(void* const* d_in, const int* in_sizes, int n_in,
                              void* d_out, int out_size, void* d_ws, size_t ws_size,
                              hipStream_t stream)
{
    const float* x      = (const float*)d_in[0];
    const int*   eidx   = (const int*)  d_in[1];
    const float* eattr  = (const float*)d_in[2];
    const float* pre_W  = (const float*)d_in[3];
    const float* pre_b  = (const float*)d_in[4];
    const float* c1_Ws  = (const float*)d_in[5];
    const float* c1_Wn  = (const float*)d_in[6];
    const float* c1_b   = (const float*)d_in[7];
    const float* c2_Ws  = (const float*)d_in[8];
    const float* c2_Wn  = (const float*)d_in[9];
    const float* c2_b   = (const float*)d_in[10];
    const float* npW    = (const float*)d_in[11];
    const float* npb    = (const float*)d_in[12];
    const float* dW0    = (const float*)d_in[13];
    const float* db0    = (const float*)d_in[14];
    const float* dW1    = (const float*)d_in[15];
    const float* db1    = (const float*)d_in[16];
    const float* dW2    = (const float*)d_in[17];
    const float* db2    = (const float*)d_in[18];
    const float* dW3    = (const float*)d_in[19];
    const float* db3    = (const float*)d_in[20];
    const float* fW     = (const float*)d_in[21];
    const float* fb     = (const float*)d_in[22];

    const int  n = in_sizes[0] / 256;
    const long E = in_sizes[1] / 2;

    char* ws = (char*)d_ws;
    size_t off = 0;
    auto alloc = [&](size_t bytes) -> void* {
        void* p = ws + off;
        off += (bytes + 255) & ~(size_t)255;
        return p;
    };
    unsigned short* B0 = (unsigned short*)alloc((size_t)n * HF * 2); // h0 -> y1
    unsigned short* B1 = (unsigned short*)alloc((size_t)n * HF * 2); // agg1 -> agg2
    unsigned short* B2 = (unsigned short*)alloc((size_t)n * HF * 2); // h1
    int*   deg    = (int*)alloc((size_t)n * sizeof(int));
    int*   bucket = (int*)alloc((size_t)n * CAP * sizeof(int));
    float* uvc    = (float*)alloc((2 * HF + 1) * sizeof(float));
    short* preWp  = (short*)alloc(256 * HF * 2);
    short* c1Wsp  = (short*)alloc(HF * HF * 2);
    short* c1Wnp  = (short*)alloc(HF * HF * 2);
    short* c2Wsp  = (short*)alloc(HF * HF * 2);
    short* c2Wnp  = (short*)alloc(HF * HF * 2);
    short* dW1p   = (short*)alloc(HF * HF * 2);
    short* dW2p   = (short*)alloc(HF * HF * 2);

    const int gemmBlocks = (n + 63) / 64;
    const int nodeBlocks = (n + 3) / 4;
    const int npass = ((n - 1) >> PSHIFT) + 1;

    repack_all<<<65, 256, 0, stream>>>(
        pre_W, c1_Ws, c1_Wn, c2_Ws, c2_Wn, dW1, dW2,
        preWp, c1Wsp, c1Wnp, c2Wsp, c2Wnp, dW1p, dW2p,
        npW, npb, dW3, db3, fW, fb, uvc);

    hipMemsetAsync(deg, 0, (size_t)n * sizeof(int), stream);
    bucket_kernel<<<2048, 256, 0, stream>>>(eidx, E, deg, bucket, npass);

    // h0 = x @ pre_W + pre_b (K=256, fp32 A converted inline)
    mfma_gemm<256, true, false, false><<<gemmBlocks, 256, 0, stream>>>(
        x, preWp, nullptr, nullptr, pre_b, B0, n);

    // agg1 = mean_agg(h0)
    agg_kernel<<<nodeBlocks, 256, 0, stream>>>(B0, deg, bucket, B1, n);

    // h1 = relu(h0@c1_Ws + agg1@c1_Wn + c1_b)
    mfma_gemm<HF, false, true, true><<<gemmBlocks, 256, 0, stream>>>(
        B0, c1Wsp, B1, c1Wnp, c1_b, B2, n);

    // y1 (dist head), reuses B0 after c1 consumed it
    disthead_kernel<<<gemmBlocks, 256, 0, stream>>>(
        eattr, dW0, db0, dW1p, db1, B0, n);

    // agg2 = mean_agg(h1)
    agg_kernel<<<nodeBlocks, 256, 0, stream>>>(B2, deg, bucket, B1, n);

    // tail: h2, y2, final dot + sigmoid
    tail_kernel<<<gemmBlocks, 256, 0, stream>>>(
        B2, B1, B0, c2Wsp, c2Wnp, dW2p, c2_b, db2, uvc, (float*)d_out, n);
}